// Round 18
// baseline (1635.879 us; speedup 1.0000x reference)
//
#include <hip/hip_runtime.h>
#include <hip/hip_bf16.h>
#include <math.h>

// Problem: B=32, S=1024, D=768, R=8.
// CONFIRMED: inputs f32 (probe bf=false). Validated: k_regiong/k_regiong32
// (r11/r16, elementwise-identical), k_num4 (r10), downstream (r2).
// r17 LESSON: __launch_bounds__ min-waves forces the register allocation that
// unlocks multi-block residency (140->124 VGPR, 2 blk/CU, 1113->610us).
// r18: k_regiong32 (BK=32, 34.8KB LDS) + __launch_bounds__(256,4):
// 4 blk/CU = 16 waves/CU. Math bit-identical to validated g/g32.
// HARD RULE: ws <= ~18.6MB.
#define NB 32
#define NS 1024
#define ND 768
#define NR 8

#define BF_THRESH_BITS 0x461C4000u   // bits of 1e4f

typedef __bf16 v8bf __attribute__((ext_vector_type(8)));
typedef float  f32x4 __attribute__((ext_vector_type(4)));

__device__ __forceinline__ float us2f(unsigned short u) {
    return __uint_as_float(((unsigned int)u) << 16);
}
__device__ __forceinline__ float ldf(const void* p, size_t i, bool bf) {
    return bf ? us2f(((const unsigned short*)p)[i]) : ((const float*)p)[i];
}
__device__ __forceinline__ unsigned short f2b_rne(float x) {
    unsigned int u = __float_as_uint(x);
    return (unsigned short)((u + 0x7fffu + ((u >> 16) & 1u)) >> 16);
}

// ---------------------------------------------------------------------------
__global__ void k_probe(const unsigned short* __restrict__ s, unsigned int* __restrict__ mb) {
    int i = blockIdx.x * 256 + threadIdx.x;
    unsigned int v = 0;
    for (int k = i; k < (1 << 22); k += 16384) {
        unsigned int b = (((unsigned int)s[k]) << 16) & 0x7fffffffu;
        v = v > b ? v : b;
    }
#pragma unroll
    for (int m = 1; m < 64; m <<= 1) {
        unsigned int o = (unsigned int)__shfl_xor((int)v, m);
        v = v > o ? v : o;
    }
    if ((threadIdx.x & 63) == 0) atomicMax(mb, v);
}

__global__ void k_wsplit(const void* __restrict__ src, int n,
                         const unsigned int* __restrict__ mb,
                         unsigned short* __restrict__ hi, unsigned short* __restrict__ lo) {
    const bool bf = (*mb < BF_THRESH_BITS);
    for (int i = blockIdx.x * 256 + threadIdx.x; i < n; i += gridDim.x * 256) {
        float x = ldf(src, i, bf);
        unsigned short h = f2b_rne(x);
        hi[i] = h;
        lo[i] = f2b_rne(x - us2f(h));
    }
}

// ---------------------------------------------------------------------------
// k_regiong32 [r16-validated math == k_regiong]: BK=32 region head.
// r18: __launch_bounds__(256,4) -> <=128 VGPR allocation, LDS 34.8KB ->
// 4 blocks/CU resident (16 waves/CU).
// Dual-view: blocks 0..511 = sat, 512..1023 = uav.
// ---------------------------------------------------------------------------
__global__ __launch_bounds__(256, 4) void k_regiong32(
    const void* __restrict__ fs, const void* __restrict__ fu,
    const unsigned short* __restrict__ iw1hi, const unsigned short* __restrict__ iw1lo,
    const void* __restrict__ ib1, const void* __restrict__ iw2, const void* __restrict__ ib2,
    const unsigned short* __restrict__ cw1hi, const unsigned short* __restrict__ cw1lo,
    const void* __restrict__ cb1, const void* __restrict__ cw2, const void* __restrict__ cb2,
    const unsigned int* __restrict__ mb,
    float* __restrict__ ws, float* __restrict__ wu)
{
    __shared__ uint4 Ah[64 * 5], Al[64 * 5];     // 5.1KB each (BK=32, pad 1)
    __shared__ uint4 Bh[128 * 5], Bl[128 * 5];   // 10.2KB each
    __shared__ float iw2s[384];
    __shared__ float part[64][9];
    // total ~34.8KB -> 4 blocks/CU with <=128 VGPR

    const bool bf = (*mb < BF_THRESH_BITS);
    const int t = threadIdx.x;
    const bool isu = (blockIdx.x >= 512);
    const void* f = isu ? fu : fs;
    float* wout = isu ? wu : ws;
    const int row0 = (isu ? blockIdx.x - 512 : blockIdx.x) * 64;

    for (int i = t; i < 384; i += 256) iw2s[i] = ldf(iw2, i, bf);

    const int lane = t & 63;
    const int wv = t >> 6;
    const int l15 = lane & 15;
    const int g = lane >> 4;

    float impacc[4] = {0.f, 0.f, 0.f, 0.f};
    float lacc[8][4];
#pragma unroll
    for (int r = 0; r < 8; r++)
#pragma unroll
        for (int x = 0; x < 4; x++) lacc[r][x] = 0.f;

    for (int nt = 0; nt < 9; nt++) {
        const bool isimp = (nt < 3);
        const int colbase = isimp ? nt * 128 : nt * 128 - 384;
        const uint4* bsh = reinterpret_cast<const uint4*>(isimp ? iw1hi : cw1hi);
        const uint4* bsl = reinterpret_cast<const uint4*>(isimp ? iw1lo : cw1lo);

        f32x4 acc[8];
        int nn[8];
#pragma unroll
        for (int cf = 0; cf < 8; cf++) {
            int n = nt * 128 + cf * 16 + l15;
            nn[cf] = n;
            float bini = isimp ? ldf(ib1, n, bf) : ldf(cb1, n - 384, bf);
            f32x4 ini = {bini, bini, bini, bini};
            acc[cf] = ini;
        }

        for (int kc = 0; kc < 24; kc++) {        // BK=32: 24 chunks
            __syncthreads();
            // stage B: 128 cols x 4 uint4 (hi+lo) = 2 each/thread
#pragma unroll
            for (int p = 0; p < 2; p++) {
                int u = t + p * 256;             // 0..511
                int cc = u >> 2, j = u & 3;
                size_t src = (size_t)(colbase + cc) * 96 + kc * 4 + j;
                Bh[cc * 5 + j] = bsh[src];
                Bl[cc * 5 + j] = bsl[src];
            }
            // stage A: 64 rows x 4 uint4 (hi+lo) = 1 each/thread
            {
                int rr = t >> 2, j = t & 3;
                if (bf) {
                    const uint4* asrc = reinterpret_cast<const uint4*>(
                        (const unsigned short*)f + (size_t)(row0 + rr) * ND);
                    Ah[rr * 5 + j] = asrc[kc * 4 + j];
                    uint4 z = {0, 0, 0, 0};
                    Al[rr * 5 + j] = z;
                } else {
                    const float* fp = (const float*)f + (size_t)(row0 + rr) * ND + kc * 32 + j * 8;
                    float4 a = *reinterpret_cast<const float4*>(fp);
                    float4 b = *reinterpret_cast<const float4*>(fp + 4);
                    float v[8] = {a.x, a.y, a.z, a.w, b.x, b.y, b.z, b.w};
                    union { unsigned short us[8]; uint4 u4; } H, L;
#pragma unroll
                    for (int e = 0; e < 8; e++) {
                        unsigned short h = f2b_rne(v[e]);
                        H.us[e] = h;
                        L.us[e] = f2b_rne(v[e] - us2f(h));
                    }
                    Ah[rr * 5 + j] = H.u4;
                    Al[rr * 5 + j] = L.u4;
                }
            }
            __syncthreads();
            // compute: one k-group of 32
            v8bf ah = __builtin_bit_cast(v8bf, Ah[(wv * 16 + l15) * 5 + g]);
            v8bf al = __builtin_bit_cast(v8bf, Al[(wv * 16 + l15) * 5 + g]);
#pragma unroll
            for (int cf = 0; cf < 8; cf++) {
                v8bf bhv = __builtin_bit_cast(v8bf, Bh[(cf * 16 + l15) * 5 + g]);
                v8bf blv = __builtin_bit_cast(v8bf, Bl[(cf * 16 + l15) * 5 + g]);
                acc[cf] = __builtin_amdgcn_mfma_f32_16x16x32_bf16(ah, bhv, acc[cf], 0, 0, 0);
                acc[cf] = __builtin_amdgcn_mfma_f32_16x16x32_bf16(al, bhv, acc[cf], 0, 0, 0);
                acc[cf] = __builtin_amdgcn_mfma_f32_16x16x32_bf16(ah, blv, acc[cf], 0, 0, 0);
            }
        }

        if (isimp) {
#pragma unroll
            for (int cf = 0; cf < 8; cf++) {
                float c = iw2s[nn[cf]];
#pragma unroll
                for (int x = 0; x < 4; x++)
                    impacc[x] = fmaf(fmaxf(acc[cf][x], 0.f), c, impacc[x]);
            }
        } else {
#pragma unroll
            for (int cf = 0; cf < 8; cf++) {
                const int nc = nn[cf] - 384;
                float h[4];
#pragma unroll
                for (int x = 0; x < 4; x++) h[x] = fmaxf(acc[cf][x], 0.f);
#pragma unroll
                for (int r = 0; r < 8; r++) {
                    float c = ldf(cw2, (size_t)r * ND + nc, bf);
#pragma unroll
                    for (int x = 0; x < 4; x++)
                        lacc[r][x] = fmaf(h[x], c, lacc[r][x]);
                }
            }
        }
    }

#pragma unroll
    for (int x = 0; x < 4; x++) {
        const int row = wv * 16 + g * 4 + x;
        float v = impacc[x];
        v += __shfl_xor(v, 1); v += __shfl_xor(v, 2);
        v += __shfl_xor(v, 4); v += __shfl_xor(v, 8);
        if (l15 == 0) part[row][0] = v;
#pragma unroll
        for (int r = 0; r < 8; r++) {
            float u = lacc[r][x];
            u += __shfl_xor(u, 1); u += __shfl_xor(u, 2);
            u += __shfl_xor(u, 4); u += __shfl_xor(u, 8);
            if (l15 == 0) part[row][1 + r] = u;
        }
    }
    __syncthreads();

    if (t < 64) {
        const int grow = row0 + t;
        float imp = part[t][0] + ldf(ib2, 0, bf);
        float lg[8], mx = -1e30f;
#pragma unroll
        for (int r = 0; r < 8; r++) { lg[r] = part[t][1 + r] + ldf(cb2, r, bf); mx = fmaxf(mx, lg[r]); }
        float ssum = 0.f;
#pragma unroll
        for (int r = 0; r < 8; r++) { lg[r] = expf(lg[r] - mx); ssum += lg[r]; }
        float inv = 1.f / ssum;
#pragma unroll
        for (int r = 0; r < 8; r++) wout[(size_t)grow * 8 + r] = imp * lg[r] * inv;
    }
}

// ---------------------------------------------------------------------------
// validated downstream pipeline [r2/r10]
// ---------------------------------------------------------------------------
__global__ __launch_bounds__(256) void k_den(const float* __restrict__ w, float* __restrict__ den) {
    __shared__ float red[256][8];
    const int b = blockIdx.x, t = threadIdx.x;
    float acc[8];
#pragma unroll
    for (int r = 0; r < 8; r++) acc[r] = 0.f;
    for (int s = t; s < NS; s += 256)
#pragma unroll
        for (int r = 0; r < 8; r++) acc[r] += w[((size_t)b * NS + s) * 8 + r];
#pragma unroll
    for (int r = 0; r < 8; r++) red[t][r] = acc[r];
    __syncthreads();
    for (int off = 128; off > 0; off >>= 1) {
        if (t < off)
#pragma unroll
            for (int r = 0; r < 8; r++) red[t][r] += red[t + off][r];
        __syncthreads();
    }
    if (t < 8) den[b * 8 + t] = red[0][t];
}

__global__ __launch_bounds__(192) void k_num4(
    const void* __restrict__ f, const float* __restrict__ w,
    const unsigned int* __restrict__ mb, float* __restrict__ nump)
{
    __shared__ float ws_[256][8];
    const bool bf = (*mb < BF_THRESH_BITS);
    const int sc = blockIdx.x, b = blockIdx.y, t = threadIdx.x;
    const int s0 = sc * 256;
    const float* wp = w + ((size_t)b * NS + s0) * 8;
    for (int i = t; i < 256 * 8; i += 192) ((float*)ws_)[i] = wp[i];
    __syncthreads();
    const int d0 = t * 4;
    float acc[8][4];
#pragma unroll
    for (int r = 0; r < 8; r++)
#pragma unroll
        for (int q = 0; q < 4; q++) acc[r][q] = 0.f;
    if (bf) {
        const unsigned short* fp = (const unsigned short*)f + ((size_t)b * NS + s0) * ND + d0;
        for (int s = 0; s < 256; s++) {
            ushort4 u = *reinterpret_cast<const ushort4*>(fp + (size_t)s * ND);
            float fv[4] = {us2f(u.x), us2f(u.y), us2f(u.z), us2f(u.w)};
#pragma unroll
            for (int r = 0; r < 8; r++) {
                float wr = ws_[s][r];
#pragma unroll
                for (int q = 0; q < 4; q++) acc[r][q] = fmaf(wr, fv[q], acc[r][q]);
            }
        }
    } else {
        const float* fp = (const float*)f + ((size_t)b * NS + s0) * ND + d0;
        for (int s = 0; s < 256; s++) {
            float4 v4 = *reinterpret_cast<const float4*>(fp + (size_t)s * ND);
            float fv[4] = {v4.x, v4.y, v4.z, v4.w};
#pragma unroll
            for (int r = 0; r < 8; r++) {
                float wr = ws_[s][r];
#pragma unroll
                for (int q = 0; q < 4; q++) acc[r][q] = fmaf(wr, fv[q], acc[r][q]);
            }
        }
    }
    float* op = nump + ((size_t)sc * NB * 8 + (size_t)b * 8) * ND;
#pragma unroll
    for (int r = 0; r < 8; r++)
#pragma unroll
        for (int q = 0; q < 4; q++) op[r * ND + d0 + q] = acc[r][q];
}

__global__ void k_regfin4(const float* __restrict__ nump, const float* __restrict__ den,
                          float* __restrict__ reg) {
    int i = blockIdx.x * 256 + threadIdx.x;
    int br = i / ND;
    float s = nump[i] + nump[196608 + i] + nump[2 * 196608 + i] + nump[3 * 196608 + i];
    reg[i] = s / (den[br] + 1e-8f);
}

__global__ __launch_bounds__(256) void k_gemm(
    const float* __restrict__ A, const void* __restrict__ W,
    const void* __restrict__ bias, float bscale,
    float* __restrict__ C, int M, int N, int K, int ldw, int col_off,
    int kchunk, int relu_fl, int atomic_fl, const unsigned int* __restrict__ mb)
{
    __shared__ float As[32][17];
    __shared__ float Ws[64][17];
    const bool bf = (*mb < BF_THRESH_BITS);
    const int t = threadIdx.x;
    const int n0 = blockIdx.x * 64, m0 = blockIdx.y * 32;
    const int kbase = blockIdx.z * kchunk;
    const int tc = t & 15, tr = t >> 4;
    float acc[2][4] = {{0, 0, 0, 0}, {0, 0, 0, 0}};
    for (int k0 = kbase; k0 < kbase + kchunk; k0 += 16) {
        __syncthreads();
        for (int i = t; i < 512; i += 256) {
            int r = i >> 4, k = i & 15;
            As[r][k] = A[(size_t)(m0 + r) * K + k0 + k];
        }
        for (int i = t; i < 1024; i += 256) {
            int r = i >> 4, k = i & 15;
            Ws[r][k] = ldf(W, (size_t)(n0 + r) * ldw + col_off + k0 + k, bf);
        }
        __syncthreads();
#pragma unroll
        for (int kk = 0; kk < 16; kk++) {
            float a0 = As[tr * 2 + 0][kk], a1 = As[tr * 2 + 1][kk];
#pragma unroll
            for (int c = 0; c < 4; c++) {
                float wv = Ws[tc * 4 + c][kk];
                acc[0][c] = fmaf(a0, wv, acc[0][c]);
                acc[1][c] = fmaf(a1, wv, acc[1][c]);
            }
        }
    }
#pragma unroll
    for (int rr = 0; rr < 2; rr++) {
        int row = m0 + tr * 2 + rr;
#pragma unroll
        for (int c = 0; c < 4; c++) {
            int col = n0 + tc * 4 + c;
            float v = acc[rr][c];
            if (atomic_fl) {
                atomicAdd(&C[(size_t)row * N + col], v);
            } else {
                if (bias) v += ldf(bias, col, bf) * bscale;
                if (relu_fl) v = fmaxf(v, 0.f);
                C[(size_t)row * N + col] = v;
            }
        }
    }
}

__global__ void k_h1(const float* __restrict__ sa, const float* __restrict__ ub,
                     const void* __restrict__ b1, const unsigned int* __restrict__ mb,
                     float* __restrict__ h1) {
    const bool bf = (*mb < BF_THRESH_BITS);
    const int p = blockIdx.x;
    const int b = p >> 6, i = (p >> 3) & 7, j = p & 7;
    const float* sap = sa + (size_t)(b * 8 + i) * ND;
    const float* ubp = ub + (size_t)(b * 8 + j) * ND;
    float* o = h1 + (size_t)p * ND;
    for (int k = threadIdx.x; k < ND; k += 256)
        o[k] = fmaxf(sap[k] + ubp[k] + ldf(b1, k, bf), 0.f);
}

__global__ void k_simscore(const float* __restrict__ h2, const void* __restrict__ w3,
                           const void* __restrict__ b3, const unsigned int* __restrict__ mb,
                           float* __restrict__ sig) {
    const bool bf = (*mb < BF_THRESH_BITS);
    const int p = blockIdx.x;
    const int lane = threadIdx.x;
    const float* hp = h2 + (size_t)p * 384;
    float v = 0.f;
    for (int k = lane; k < 384; k += 64) v = fmaf(hp[k], ldf(w3, k, bf), v);
#pragma unroll
    for (int m = 1; m < 64; m <<= 1) v += __shfl_xor(v, m);
    if (lane == 0) sig[p] = 1.f / (1.f + expf(-(v + ldf(b3, 0, bf))));
}

__global__ void k_simred(const float* __restrict__ sig, float* __restrict__ simacc) {
    const int q = threadIdx.x;
    float s = 0.f;
    for (int b = 0; b < 32; b++) s += sig[b * 64 + q];
    simacc[q] = s * (1.f / 32.f);
}

__global__ void k_match(const float* __restrict__ simacc, int* __restrict__ perm) {
    if (threadIdx.x == 0) {
        float sim[64];
        bool used[8] = {false, false, false, false, false, false, false, false};
        for (int i = 0; i < 64; i++) sim[i] = simacc[i];
        for (int i = 0; i < 8; i++) {
            int bj = 0; float bvv = -2.f;
            for (int j = 0; j < 8; j++) {
                float v = used[j] ? -1.f : sim[i * 8 + j];
                if (v > bvv) { bvv = v; bj = j; }
            }
            used[bj] = true;
            perm[i] = bj;
        }
    }
}

__global__ void k_tbuild(const float* __restrict__ satr, const float* __restrict__ uavr,
                         const int* __restrict__ perm, float* __restrict__ tb) {
    const int row = blockIdx.x;
    const int b = row >> 3, i = row & 7;
    const float* sp = satr + (size_t)row * ND;
    const float* up = uavr + (size_t)(b * 8 + perm[i]) * ND;
    float* o = tb + (size_t)row * ND;
    for (int k = threadIdx.x; k < ND; k += 256) o[k] = sp[k] + up[k];
}

__global__ __launch_bounds__(256) void k_ln(const float* __restrict__ x,
                                            const void* __restrict__ g,
                                            const void* __restrict__ b,
                                            const unsigned int* __restrict__ mb,
                                            float* __restrict__ o) {
    __shared__ float t0[4], t1[4];
    const bool bf = (*mb < BF_THRESH_BITS);
    const int row = blockIdx.x, tid = threadIdx.x;
    const float* xp = x + (size_t)row * ND;
    float v0 = xp[tid], v1 = xp[tid + 256], v2 = xp[tid + 512];
    float s = v0 + v1 + v2;
#pragma unroll
    for (int m = 1; m < 64; m <<= 1) s += __shfl_xor(s, m);
    if ((tid & 63) == 0) t0[tid >> 6] = s;
    __syncthreads();
    float mean = (t0[0] + t0[1] + t0[2] + t0[3]) * (1.f / 768.f);
    float d0 = v0 - mean, d1 = v1 - mean, d2 = v2 - mean;
    float q = d0 * d0 + d1 * d1 + d2 * d2;
#pragma unroll
    for (int m = 1; m < 64; m <<= 1) q += __shfl_xor(q, m);
    if ((tid & 63) == 0) t1[tid >> 6] = q;
    __syncthreads();
    float var = (t1[0] + t1[1] + t1[2] + t1[3]) * (1.f / 768.f);
    float inv = 1.f / sqrtf(var + 1e-5f);
    float* op = o + (size_t)row * ND;
    op[tid]       = d0 * inv * ldf(g, tid, bf)       + ldf(b, tid, bf);
    op[tid + 256] = d1 * inv * ldf(g, tid + 256, bf) + ldf(b, tid + 256, bf);
    op[tid + 512] = d2 * inv * ldf(g, tid + 512, bf) + ldf(b, tid + 512, bf);
}

__global__ __launch_bounds__(256) void k_fusln(const float* __restrict__ y,
                                               const void* __restrict__ fb,
                                               const void* __restrict__ g,
                                               const void* __restrict__ bb,
                                               const unsigned int* __restrict__ mb,
                                               void* __restrict__ out) {
    __shared__ float t0[4], t1[4];
    const bool bf = (*mb < BF_THRESH_BITS);
    const int row = blockIdx.x, tid = threadIdx.x;
    const float* yp = y + (size_t)row * ND;
    float v0 = yp[tid] + ldf(fb, tid, bf);
    float v1 = yp[tid + 256] + ldf(fb, tid + 256, bf);
    float v2 = yp[tid + 512] + ldf(fb, tid + 512, bf);
    float s = v0 + v1 + v2;
#pragma unroll
    for (int m = 1; m < 64; m <<= 1) s += __shfl_xor(s, m);
    if ((tid & 63) == 0) t0[tid >> 6] = s;
    __syncthreads();
    float mean = (t0[0] + t0[1] + t0[2] + t0[3]) * (1.f / 768.f);
    float d0 = v0 - mean, d1 = v1 - mean, d2 = v2 - mean;
    float q = d0 * d0 + d1 * d1 + d2 * d2;
#pragma unroll
    for (int m = 1; m < 64; m <<= 1) q += __shfl_xor(q, m);
    if ((tid & 63) == 0) t1[tid >> 6] = q;
    __syncthreads();
    float var = (t1[0] + t1[1] + t1[2] + t1[3]) * (1.f / 768.f);
    float inv = 1.f / sqrtf(var + 1e-5f);
    float r0 = fmaxf(d0 * inv * ldf(g, tid, bf)       + ldf(bb, tid, bf), 0.f);
    float r1 = fmaxf(d1 * inv * ldf(g, tid + 256, bf) + ldf(bb, tid + 256, bf), 0.f);
    float r2 = fmaxf(d2 * inv * ldf(g, tid + 512, bf) + ldf(bb, tid + 512, bf), 0.f);
    if (bf) {
        __hip_bfloat16* op = (__hip_bfloat16*)out + (size_t)row * ND;
        op[tid]       = __float2bfloat16(r0);
        op[tid + 256] = __float2bfloat16(r1);
        op[tid + 512] = __float2bfloat16(r2);
    } else {
        float* op = (float*)out + (size_t)row * ND;
        op[tid]       = r0;
        op[tid + 256] = r1;
        op[tid + 512] = r2;
    }
}

// ---------------------------------------------------------------------------
extern "C" void kernel_launch(void* const* d_in, const int* in_sizes, int n_in,
                              void* d_out, int out_size, void* d_ws, size_t ws_size,
                              hipStream_t stream)
{
    (void)in_sizes; (void)n_in; (void)out_size; (void)ws_size;
    const void* sat = d_in[0];
    const void* uav = d_in[1];
    const void* iw1 = d_in[2];
    const void* ib1 = d_in[3];
    const void* iw2 = d_in[4];
    const void* ib2 = d_in[5];
    const void* cw1 = d_in[6];
    const void* cb1 = d_in[7];
    const void* cw2 = d_in[8];
    const void* cb2 = d_in[9];
    const void* sw1 = d_in[10];
    const void* sb1 = d_in[11];
    const void* sw2 = d_in[12];
    const void* sb2 = d_in[13];
    const void* sw3 = d_in[14];
    const void* sb3 = d_in[15];
    // d_in[16..19] = wq,bq,wk,bk: unused (kv len-1 softmax == 1)
    const void* wv_ = d_in[20];
    const void* bv_ = d_in[21];
    const void* wo_ = d_in[22];
    const void* bo_ = d_in[23];
    const void* lng = d_in[24];
    const void* lnb = d_in[25];
    const void* fw  = d_in[26];
    const void* fb  = d_in[27];
    const void* fg  = d_in[28];
    const void* fbb = d_in[29];

    char* wsb = (char*)d_ws;
    size_t off = 0;
    auto take = [&](size_t n) { void* p = wsb + off; off += (n + 511) & ~(size_t)511; return p; };
    unsigned int* mb = (unsigned int*)take(4);
    float* w_sat = (float*)take((size_t)NB * NS * 8 * 4);
    float* w_uav = (float*)take((size_t)NB * NS * 8 * 4);
    float* den_s = (float*)take(256 * 4);
    float* den_u = (float*)take(256 * 4);
    float* satr  = (float*)take((size_t)NB * 8 * ND * 4);
    float* uavr  = (float*)take((size_t)NB * 8 * ND * 4);
    float* sa    = (float*)take((size_t)256 * ND * 4);
    float* ub    = (float*)take((size_t)256 * ND * 4);
    float* h1    = (float*)take((size_t)2048 * ND * 4);
    float* h2    = (float*)take((size_t)2048 * 384 * 4);
    float* sig   = (float*)take(2048 * 4);
    float* simac = (float*)take(64 * 4);
    int*   perm  = (int*)take(64);
    float* tb    = (float*)take((size_t)256 * ND * 4);
    float* vb    = (float*)take((size_t)256 * ND * 4);
    float* pb    = (float*)take((size_t)256 * ND * 4);
    float* pool  = (float*)take((size_t)256 * ND * 4);
    float* yb    = (float*)take((size_t)NB * ND * 4);
    // aliases inside h1 (first written much later by k_h1): split weights
    unsigned short* wsp = (unsigned short*)h1;
    unsigned short* iw1hi = wsp;
    unsigned short* iw1lo = wsp + (size_t)294912;
    unsigned short* cw1hi = wsp + (size_t)589824;
    unsigned short* cw1lo = wsp + (size_t)1179648;
    // alias inside h2 (first written by gemm later): num partials (3.1MB)
    float* nump4 = h2;
    // total ws ≈ 17.5 MB

    hipMemsetAsync(mb, 0, 4, stream);
    hipMemsetAsync(yb, 0, (size_t)NB * ND * 4, stream);

    k_probe<<<64, 256, 0, stream>>>((const unsigned short*)sat, mb);

    k_wsplit<<<512, 256, 0, stream>>>(iw1, 294912, mb, iw1hi, iw1lo);
    k_wsplit<<<512, 256, 0, stream>>>(cw1, 589824, mb, cw1hi, cw1lo);

    // region head (validated r16 math; r18 occupancy fix) -> w directly
    k_regiong32<<<1024, 256, 0, stream>>>(sat, uav, iw1hi, iw1lo, ib1, iw2, ib2,
                                          cw1hi, cw1lo, cb1, cw2, cb2, mb, w_sat, w_uav);

    // downstream (validated)
    k_den<<<32, 256, 0, stream>>>(w_sat, den_s);
    k_den<<<32, 256, 0, stream>>>(w_uav, den_u);
    k_num4<<<dim3(4, 32), 192, 0, stream>>>(sat, w_sat, mb, nump4);
    k_regfin4<<<768, 256, 0, stream>>>(nump4, den_s, satr);
    k_num4<<<dim3(4, 32), 192, 0, stream>>>(uav, w_uav, mb, nump4);
    k_regfin4<<<768, 256, 0, stream>>>(nump4, den_u, uavr);

    k_gemm<<<dim3(12, 8, 1), 256, 0, stream>>>(satr, sw1, nullptr, 0.f, sa, 256, 768, 768, 1536, 0,   768, 0, 0, mb);
    k_gemm<<<dim3(12, 8, 1), 256, 0, stream>>>(uavr, sw1, nullptr, 0.f, ub, 256, 768, 768, 1536, 768, 768, 0, 0, mb);
    k_h1<<<2048, 256, 0, stream>>>(sa, ub, sb1, mb, h1);
    k_gemm<<<dim3(6, 64, 1), 256, 0, stream>>>(h1, sw2, sb2, 1.f, h2, 2048, 384, 768, 768, 0, 768, 1, 0, mb);
    k_simscore<<<2048, 64, 0, stream>>>(h2, sw3, sb3, mb, sig);
    k_simred<<<1, 64, 0, stream>>>(sig, simac);
    k_match<<<1, 64, 0, stream>>>(simac, perm);

    k_tbuild<<<256, 256, 0, stream>>>(satr, uavr, perm, tb);
    k_gemm<<<dim3(12, 8, 1), 256, 0, stream>>>(tb, wv_, bv_, 2.f, vb, 256, 768, 768, 768, 0, 768, 0, 0, mb);
    k_gemm<<<dim3(12, 8, 1), 256, 0, stream>>>(vb, wo_, bo_, 2.f, pb, 256, 768, 768, 768, 0, 768, 0, 0, mb);
    k_ln<<<256, 256, 0, stream>>>(pb, lng, lnb, mb, pool);

    k_gemm<<<dim3(12, 1, 8), 256, 0, stream>>>(pool, fw, nullptr, 0.f, yb, 32, 768, 6144, 6144, 0, 768, 0, 1, mb);
    k_fusln<<<32, 256, 0, stream>>>(yb, fb, fg, fbb, mb, d_out);
}

// Round 19
// 1610.134 us; speedup vs baseline: 1.0160x; 1.0160x over previous
//
#include <hip/hip_runtime.h>
#include <hip/hip_bf16.h>
#include <math.h>

// Problem: B=32, S=1024, D=768, R=8.
// CONFIRMED: inputs f32 (probe bf=false). Validated: k_regiong/k_regiong32
// (r11/r16, elementwise-identical), k_num4 (r10), downstream (r2).
// Register-budget model (r16-r18): budget = 512/min_waves.
//   (256,2)->256 regs: no spill, 2 blk/CU, 610us (r17 best so far)
//   (256,4)->128 regs: SPILL (WRITE 658MB), 884us (r18)
// r19: (256,3) -> ~170 regs, g32 needs ~136 -> no spill, 3 blk/CU, 12 waves.
// HARD RULE: ws <= ~18.6MB.
#define NB 32
#define NS 1024
#define ND 768
#define NR 8

#define BF_THRESH_BITS 0x461C4000u   // bits of 1e4f

typedef __bf16 v8bf __attribute__((ext_vector_type(8)));
typedef float  f32x4 __attribute__((ext_vector_type(4)));

__device__ __forceinline__ float us2f(unsigned short u) {
    return __uint_as_float(((unsigned int)u) << 16);
}
__device__ __forceinline__ float ldf(const void* p, size_t i, bool bf) {
    return bf ? us2f(((const unsigned short*)p)[i]) : ((const float*)p)[i];
}
__device__ __forceinline__ unsigned short f2b_rne(float x) {
    unsigned int u = __float_as_uint(x);
    return (unsigned short)((u + 0x7fffu + ((u >> 16) & 1u)) >> 16);
}

// ---------------------------------------------------------------------------
__global__ void k_probe(const unsigned short* __restrict__ s, unsigned int* __restrict__ mb) {
    int i = blockIdx.x * 256 + threadIdx.x;
    unsigned int v = 0;
    for (int k = i; k < (1 << 22); k += 16384) {
        unsigned int b = (((unsigned int)s[k]) << 16) & 0x7fffffffu;
        v = v > b ? v : b;
    }
#pragma unroll
    for (int m = 1; m < 64; m <<= 1) {
        unsigned int o = (unsigned int)__shfl_xor((int)v, m);
        v = v > o ? v : o;
    }
    if ((threadIdx.x & 63) == 0) atomicMax(mb, v);
}

__global__ void k_wsplit(const void* __restrict__ src, int n,
                         const unsigned int* __restrict__ mb,
                         unsigned short* __restrict__ hi, unsigned short* __restrict__ lo) {
    const bool bf = (*mb < BF_THRESH_BITS);
    for (int i = blockIdx.x * 256 + threadIdx.x; i < n; i += gridDim.x * 256) {
        float x = ldf(src, i, bf);
        unsigned short h = f2b_rne(x);
        hi[i] = h;
        lo[i] = f2b_rne(x - us2f(h));
    }
}

// ---------------------------------------------------------------------------
// k_regiong32 [r16-validated math]: BK=32 region head.
// r19: __launch_bounds__(256,3) -> ~170-reg budget (fits 136, no spill),
// LDS 34.8KB -> 3 blocks/CU, 12 waves/CU.
// Dual-view: blocks 0..511 = sat, 512..1023 = uav.
// ---------------------------------------------------------------------------
__global__ __launch_bounds__(256, 3) void k_regiong32(
    const void* __restrict__ fs, const void* __restrict__ fu,
    const unsigned short* __restrict__ iw1hi, const unsigned short* __restrict__ iw1lo,
    const void* __restrict__ ib1, const void* __restrict__ iw2, const void* __restrict__ ib2,
    const unsigned short* __restrict__ cw1hi, const unsigned short* __restrict__ cw1lo,
    const void* __restrict__ cb1, const void* __restrict__ cw2, const void* __restrict__ cb2,
    const unsigned int* __restrict__ mb,
    float* __restrict__ ws, float* __restrict__ wu)
{
    __shared__ uint4 Ah[64 * 5], Al[64 * 5];     // 5.1KB each (BK=32, pad 1)
    __shared__ uint4 Bh[128 * 5], Bl[128 * 5];   // 10.2KB each
    __shared__ float iw2s[384];
    __shared__ float part[64][9];
    // total ~34.8KB -> 3 blocks/CU at <=~170 VGPR

    const bool bf = (*mb < BF_THRESH_BITS);
    const int t = threadIdx.x;
    const bool isu = (blockIdx.x >= 512);
    const void* f = isu ? fu : fs;
    float* wout = isu ? wu : ws;
    const int row0 = (isu ? blockIdx.x - 512 : blockIdx.x) * 64;

    for (int i = t; i < 384; i += 256) iw2s[i] = ldf(iw2, i, bf);

    const int lane = t & 63;
    const int wv = t >> 6;
    const int l15 = lane & 15;
    const int g = lane >> 4;

    float impacc[4] = {0.f, 0.f, 0.f, 0.f};
    float lacc[8][4];
#pragma unroll
    for (int r = 0; r < 8; r++)
#pragma unroll
        for (int x = 0; x < 4; x++) lacc[r][x] = 0.f;

    for (int nt = 0; nt < 9; nt++) {
        const bool isimp = (nt < 3);
        const int colbase = isimp ? nt * 128 : nt * 128 - 384;
        const uint4* bsh = reinterpret_cast<const uint4*>(isimp ? iw1hi : cw1hi);
        const uint4* bsl = reinterpret_cast<const uint4*>(isimp ? iw1lo : cw1lo);

        f32x4 acc[8];
        int nn[8];
#pragma unroll
        for (int cf = 0; cf < 8; cf++) {
            int n = nt * 128 + cf * 16 + l15;
            nn[cf] = n;
            float bini = isimp ? ldf(ib1, n, bf) : ldf(cb1, n - 384, bf);
            f32x4 ini = {bini, bini, bini, bini};
            acc[cf] = ini;
        }

        for (int kc = 0; kc < 24; kc++) {        // BK=32: 24 chunks
            __syncthreads();
            // stage B: 128 cols x 4 uint4 (hi+lo) = 2 each/thread
#pragma unroll
            for (int p = 0; p < 2; p++) {
                int u = t + p * 256;             // 0..511
                int cc = u >> 2, j = u & 3;
                size_t src = (size_t)(colbase + cc) * 96 + kc * 4 + j;
                Bh[cc * 5 + j] = bsh[src];
                Bl[cc * 5 + j] = bsl[src];
            }
            // stage A: 64 rows x 4 uint4 (hi+lo) = 1 each/thread
            {
                int rr = t >> 2, j = t & 3;
                if (bf) {
                    const uint4* asrc = reinterpret_cast<const uint4*>(
                        (const unsigned short*)f + (size_t)(row0 + rr) * ND);
                    Ah[rr * 5 + j] = asrc[kc * 4 + j];
                    uint4 z = {0, 0, 0, 0};
                    Al[rr * 5 + j] = z;
                } else {
                    const float* fp = (const float*)f + (size_t)(row0 + rr) * ND + kc * 32 + j * 8;
                    float4 a = *reinterpret_cast<const float4*>(fp);
                    float4 b = *reinterpret_cast<const float4*>(fp + 4);
                    float v[8] = {a.x, a.y, a.z, a.w, b.x, b.y, b.z, b.w};
                    union { unsigned short us[8]; uint4 u4; } H, L;
#pragma unroll
                    for (int e = 0; e < 8; e++) {
                        unsigned short h = f2b_rne(v[e]);
                        H.us[e] = h;
                        L.us[e] = f2b_rne(v[e] - us2f(h));
                    }
                    Ah[rr * 5 + j] = H.u4;
                    Al[rr * 5 + j] = L.u4;
                }
            }
            __syncthreads();
            // compute: one k-group of 32
            v8bf ah = __builtin_bit_cast(v8bf, Ah[(wv * 16 + l15) * 5 + g]);
            v8bf al = __builtin_bit_cast(v8bf, Al[(wv * 16 + l15) * 5 + g]);
#pragma unroll
            for (int cf = 0; cf < 8; cf++) {
                v8bf bhv = __builtin_bit_cast(v8bf, Bh[(cf * 16 + l15) * 5 + g]);
                v8bf blv = __builtin_bit_cast(v8bf, Bl[(cf * 16 + l15) * 5 + g]);
                acc[cf] = __builtin_amdgcn_mfma_f32_16x16x32_bf16(ah, bhv, acc[cf], 0, 0, 0);
                acc[cf] = __builtin_amdgcn_mfma_f32_16x16x32_bf16(al, bhv, acc[cf], 0, 0, 0);
                acc[cf] = __builtin_amdgcn_mfma_f32_16x16x32_bf16(ah, blv, acc[cf], 0, 0, 0);
            }
        }

        if (isimp) {
#pragma unroll
            for (int cf = 0; cf < 8; cf++) {
                float c = iw2s[nn[cf]];
#pragma unroll
                for (int x = 0; x < 4; x++)
                    impacc[x] = fmaf(fmaxf(acc[cf][x], 0.f), c, impacc[x]);
            }
        } else {
#pragma unroll
            for (int cf = 0; cf < 8; cf++) {
                const int nc = nn[cf] - 384;
                float h[4];
#pragma unroll
                for (int x = 0; x < 4; x++) h[x] = fmaxf(acc[cf][x], 0.f);
#pragma unroll
                for (int r = 0; r < 8; r++) {
                    float c = ldf(cw2, (size_t)r * ND + nc, bf);
#pragma unroll
                    for (int x = 0; x < 4; x++)
                        lacc[r][x] = fmaf(h[x], c, lacc[r][x]);
                }
            }
        }
    }

#pragma unroll
    for (int x = 0; x < 4; x++) {
        const int row = wv * 16 + g * 4 + x;
        float v = impacc[x];
        v += __shfl_xor(v, 1); v += __shfl_xor(v, 2);
        v += __shfl_xor(v, 4); v += __shfl_xor(v, 8);
        if (l15 == 0) part[row][0] = v;
#pragma unroll
        for (int r = 0; r < 8; r++) {
            float u = lacc[r][x];
            u += __shfl_xor(u, 1); u += __shfl_xor(u, 2);
            u += __shfl_xor(u, 4); u += __shfl_xor(u, 8);
            if (l15 == 0) part[row][1 + r] = u;
        }
    }
    __syncthreads();

    if (t < 64) {
        const int grow = row0 + t;
        float imp = part[t][0] + ldf(ib2, 0, bf);
        float lg[8], mx = -1e30f;
#pragma unroll
        for (int r = 0; r < 8; r++) { lg[r] = part[t][1 + r] + ldf(cb2, r, bf); mx = fmaxf(mx, lg[r]); }
        float ssum = 0.f;
#pragma unroll
        for (int r = 0; r < 8; r++) { lg[r] = expf(lg[r] - mx); ssum += lg[r]; }
        float inv = 1.f / ssum;
#pragma unroll
        for (int r = 0; r < 8; r++) wout[(size_t)grow * 8 + r] = imp * lg[r] * inv;
    }
}

// ---------------------------------------------------------------------------
// validated downstream pipeline [r2/r10]
// ---------------------------------------------------------------------------
__global__ __launch_bounds__(256) void k_den(const float* __restrict__ w, float* __restrict__ den) {
    __shared__ float red[256][8];
    const int b = blockIdx.x, t = threadIdx.x;
    float acc[8];
#pragma unroll
    for (int r = 0; r < 8; r++) acc[r] = 0.f;
    for (int s = t; s < NS; s += 256)
#pragma unroll
        for (int r = 0; r < 8; r++) acc[r] += w[((size_t)b * NS + s) * 8 + r];
#pragma unroll
    for (int r = 0; r < 8; r++) red[t][r] = acc[r];
    __syncthreads();
    for (int off = 128; off > 0; off >>= 1) {
        if (t < off)
#pragma unroll
            for (int r = 0; r < 8; r++) red[t][r] += red[t + off][r];
        __syncthreads();
    }
    if (t < 8) den[b * 8 + t] = red[0][t];
}

__global__ __launch_bounds__(192) void k_num4(
    const void* __restrict__ f, const float* __restrict__ w,
    const unsigned int* __restrict__ mb, float* __restrict__ nump)
{
    __shared__ float ws_[256][8];
    const bool bf = (*mb < BF_THRESH_BITS);
    const int sc = blockIdx.x, b = blockIdx.y, t = threadIdx.x;
    const int s0 = sc * 256;
    const float* wp = w + ((size_t)b * NS + s0) * 8;
    for (int i = t; i < 256 * 8; i += 192) ((float*)ws_)[i] = wp[i];
    __syncthreads();
    const int d0 = t * 4;
    float acc[8][4];
#pragma unroll
    for (int r = 0; r < 8; r++)
#pragma unroll
        for (int q = 0; q < 4; q++) acc[r][q] = 0.f;
    if (bf) {
        const unsigned short* fp = (const unsigned short*)f + ((size_t)b * NS + s0) * ND + d0;
        for (int s = 0; s < 256; s++) {
            ushort4 u = *reinterpret_cast<const ushort4*>(fp + (size_t)s * ND);
            float fv[4] = {us2f(u.x), us2f(u.y), us2f(u.z), us2f(u.w)};
#pragma unroll
            for (int r = 0; r < 8; r++) {
                float wr = ws_[s][r];
#pragma unroll
                for (int q = 0; q < 4; q++) acc[r][q] = fmaf(wr, fv[q], acc[r][q]);
            }
        }
    } else {
        const float* fp = (const float*)f + ((size_t)b * NS + s0) * ND + d0;
        for (int s = 0; s < 256; s++) {
            float4 v4 = *reinterpret_cast<const float4*>(fp + (size_t)s * ND);
            float fv[4] = {v4.x, v4.y, v4.z, v4.w};
#pragma unroll
            for (int r = 0; r < 8; r++) {
                float wr = ws_[s][r];
#pragma unroll
                for (int q = 0; q < 4; q++) acc[r][q] = fmaf(wr, fv[q], acc[r][q]);
            }
        }
    }
    float* op = nump + ((size_t)sc * NB * 8 + (size_t)b * 8) * ND;
#pragma unroll
    for (int r = 0; r < 8; r++)
#pragma unroll
        for (int q = 0; q < 4; q++) op[r * ND + d0 + q] = acc[r][q];
}

__global__ void k_regfin4(const float* __restrict__ nump, const float* __restrict__ den,
                          float* __restrict__ reg) {
    int i = blockIdx.x * 256 + threadIdx.x;
    int br = i / ND;
    float s = nump[i] + nump[196608 + i] + nump[2 * 196608 + i] + nump[3 * 196608 + i];
    reg[i] = s / (den[br] + 1e-8f);
}

__global__ __launch_bounds__(256) void k_gemm(
    const float* __restrict__ A, const void* __restrict__ W,
    const void* __restrict__ bias, float bscale,
    float* __restrict__ C, int M, int N, int K, int ldw, int col_off,
    int kchunk, int relu_fl, int atomic_fl, const unsigned int* __restrict__ mb)
{
    __shared__ float As[32][17];
    __shared__ float Ws[64][17];
    const bool bf = (*mb < BF_THRESH_BITS);
    const int t = threadIdx.x;
    const int n0 = blockIdx.x * 64, m0 = blockIdx.y * 32;
    const int kbase = blockIdx.z * kchunk;
    const int tc = t & 15, tr = t >> 4;
    float acc[2][4] = {{0, 0, 0, 0}, {0, 0, 0, 0}};
    for (int k0 = kbase; k0 < kbase + kchunk; k0 += 16) {
        __syncthreads();
        for (int i = t; i < 512; i += 256) {
            int r = i >> 4, k = i & 15;
            As[r][k] = A[(size_t)(m0 + r) * K + k0 + k];
        }
        for (int i = t; i < 1024; i += 256) {
            int r = i >> 4, k = i & 15;
            Ws[r][k] = ldf(W, (size_t)(n0 + r) * ldw + col_off + k0 + k, bf);
        }
        __syncthreads();
#pragma unroll
        for (int kk = 0; kk < 16; kk++) {
            float a0 = As[tr * 2 + 0][kk], a1 = As[tr * 2 + 1][kk];
#pragma unroll
            for (int c = 0; c < 4; c++) {
                float wv = Ws[tc * 4 + c][kk];
                acc[0][c] = fmaf(a0, wv, acc[0][c]);
                acc[1][c] = fmaf(a1, wv, acc[1][c]);
            }
        }
    }
#pragma unroll
    for (int rr = 0; rr < 2; rr++) {
        int row = m0 + tr * 2 + rr;
#pragma unroll
        for (int c = 0; c < 4; c++) {
            int col = n0 + tc * 4 + c;
            float v = acc[rr][c];
            if (atomic_fl) {
                atomicAdd(&C[(size_t)row * N + col], v);
            } else {
                if (bias) v += ldf(bias, col, bf) * bscale;
                if (relu_fl) v = fmaxf(v, 0.f);
                C[(size_t)row * N + col] = v;
            }
        }
    }
}

__global__ void k_h1(const float* __restrict__ sa, const float* __restrict__ ub,
                     const void* __restrict__ b1, const unsigned int* __restrict__ mb,
                     float* __restrict__ h1) {
    const bool bf = (*mb < BF_THRESH_BITS);
    const int p = blockIdx.x;
    const int b = p >> 6, i = (p >> 3) & 7, j = p & 7;
    const float* sap = sa + (size_t)(b * 8 + i) * ND;
    const float* ubp = ub + (size_t)(b * 8 + j) * ND;
    float* o = h1 + (size_t)p * ND;
    for (int k = threadIdx.x; k < ND; k += 256)
        o[k] = fmaxf(sap[k] + ubp[k] + ldf(b1, k, bf), 0.f);
}

__global__ void k_simscore(const float* __restrict__ h2, const void* __restrict__ w3,
                           const void* __restrict__ b3, const unsigned int* __restrict__ mb,
                           float* __restrict__ sig) {
    const bool bf = (*mb < BF_THRESH_BITS);
    const int p = blockIdx.x;
    const int lane = threadIdx.x;
    const float* hp = h2 + (size_t)p * 384;
    float v = 0.f;
    for (int k = lane; k < 384; k += 64) v = fmaf(hp[k], ldf(w3, k, bf), v);
#pragma unroll
    for (int m = 1; m < 64; m <<= 1) v += __shfl_xor(v, m);
    if (lane == 0) sig[p] = 1.f / (1.f + expf(-(v + ldf(b3, 0, bf))));
}

__global__ void k_simred(const float* __restrict__ sig, float* __restrict__ simacc) {
    const int q = threadIdx.x;
    float s = 0.f;
    for (int b = 0; b < 32; b++) s += sig[b * 64 + q];
    simacc[q] = s * (1.f / 32.f);
}

__global__ void k_match(const float* __restrict__ simacc, int* __restrict__ perm) {
    if (threadIdx.x == 0) {
        float sim[64];
        bool used[8] = {false, false, false, false, false, false, false, false};
        for (int i = 0; i < 64; i++) sim[i] = simacc[i];
        for (int i = 0; i < 8; i++) {
            int bj = 0; float bvv = -2.f;
            for (int j = 0; j < 8; j++) {
                float v = used[j] ? -1.f : sim[i * 8 + j];
                if (v > bvv) { bvv = v; bj = j; }
            }
            used[bj] = true;
            perm[i] = bj;
        }
    }
}

__global__ void k_tbuild(const float* __restrict__ satr, const float* __restrict__ uavr,
                         const int* __restrict__ perm, float* __restrict__ tb) {
    const int row = blockIdx.x;
    const int b = row >> 3, i = row & 7;
    const float* sp = satr + (size_t)row * ND;
    const float* up = uavr + (size_t)(b * 8 + perm[i]) * ND;
    float* o = tb + (size_t)row * ND;
    for (int k = threadIdx.x; k < ND; k += 256) o[k] = sp[k] + up[k];
}

__global__ __launch_bounds__(256) void k_ln(const float* __restrict__ x,
                                            const void* __restrict__ g,
                                            const void* __restrict__ b,
                                            const unsigned int* __restrict__ mb,
                                            float* __restrict__ o) {
    __shared__ float t0[4], t1[4];
    const bool bf = (*mb < BF_THRESH_BITS);
    const int row = blockIdx.x, tid = threadIdx.x;
    const float* xp = x + (size_t)row * ND;
    float v0 = xp[tid], v1 = xp[tid + 256], v2 = xp[tid + 512];
    float s = v0 + v1 + v2;
#pragma unroll
    for (int m = 1; m < 64; m <<= 1) s += __shfl_xor(s, m);
    if ((tid & 63) == 0) t0[tid >> 6] = s;
    __syncthreads();
    float mean = (t0[0] + t0[1] + t0[2] + t0[3]) * (1.f / 768.f);
    float d0 = v0 - mean, d1 = v1 - mean, d2 = v2 - mean;
    float q = d0 * d0 + d1 * d1 + d2 * d2;
#pragma unroll
    for (int m = 1; m < 64; m <<= 1) q += __shfl_xor(q, m);
    if ((tid & 63) == 0) t1[tid >> 6] = q;
    __syncthreads();
    float var = (t1[0] + t1[1] + t1[2] + t1[3]) * (1.f / 768.f);
    float inv = 1.f / sqrtf(var + 1e-5f);
    float* op = o + (size_t)row * ND;
    op[tid]       = d0 * inv * ldf(g, tid, bf)       + ldf(b, tid, bf);
    op[tid + 256] = d1 * inv * ldf(g, tid + 256, bf) + ldf(b, tid + 256, bf);
    op[tid + 512] = d2 * inv * ldf(g, tid + 512, bf) + ldf(b, tid + 512, bf);
}

__global__ __launch_bounds__(256) void k_fusln(const float* __restrict__ y,
                                               const void* __restrict__ fb,
                                               const void* __restrict__ g,
                                               const void* __restrict__ bb,
                                               const unsigned int* __restrict__ mb,
                                               void* __restrict__ out) {
    __shared__ float t0[4], t1[4];
    const bool bf = (*mb < BF_THRESH_BITS);
    const int row = blockIdx.x, tid = threadIdx.x;
    const float* yp = y + (size_t)row * ND;
    float v0 = yp[tid] + ldf(fb, tid, bf);
    float v1 = yp[tid + 256] + ldf(fb, tid + 256, bf);
    float v2 = yp[tid + 512] + ldf(fb, tid + 512, bf);
    float s = v0 + v1 + v2;
#pragma unroll
    for (int m = 1; m < 64; m <<= 1) s += __shfl_xor(s, m);
    if ((tid & 63) == 0) t0[tid >> 6] = s;
    __syncthreads();
    float mean = (t0[0] + t0[1] + t0[2] + t0[3]) * (1.f / 768.f);
    float d0 = v0 - mean, d1 = v1 - mean, d2 = v2 - mean;
    float q = d0 * d0 + d1 * d1 + d2 * d2;
#pragma unroll
    for (int m = 1; m < 64; m <<= 1) q += __shfl_xor(q, m);
    if ((tid & 63) == 0) t1[tid >> 6] = q;
    __syncthreads();
    float var = (t1[0] + t1[1] + t1[2] + t1[3]) * (1.f / 768.f);
    float inv = 1.f / sqrtf(var + 1e-5f);
    float r0 = fmaxf(d0 * inv * ldf(g, tid, bf)       + ldf(bb, tid, bf), 0.f);
    float r1 = fmaxf(d1 * inv * ldf(g, tid + 256, bf) + ldf(bb, tid + 256, bf), 0.f);
    float r2 = fmaxf(d2 * inv * ldf(g, tid + 512, bf) + ldf(bb, tid + 512, bf), 0.f);
    if (bf) {
        __hip_bfloat16* op = (__hip_bfloat16*)out + (size_t)row * ND;
        op[tid]       = __float2bfloat16(r0);
        op[tid + 256] = __float2bfloat16(r1);
        op[tid + 512] = __float2bfloat16(r2);
    } else {
        float* op = (float*)out + (size_t)row * ND;
        op[tid]       = r0;
        op[tid + 256] = r1;
        op[tid + 512] = r2;
    }
}

// ---------------------------------------------------------------------------
extern "C" void kernel_launch(void* const* d_in, const int* in_sizes, int n_in,
                              void* d_out, int out_size, void* d_ws, size_t ws_size,
                              hipStream_t stream)
{
    (void)in_sizes; (void)n_in; (void)out_size; (void)ws_size;
    const void* sat = d_in[0];
    const void* uav = d_in[1];
    const void* iw1 = d_in[2];
    const void* ib1 = d_in[3];
    const void* iw2 = d_in[4];
    const void* ib2 = d_in[5];
    const void* cw1 = d_in[6];
    const void* cb1 = d_in[7];
    const void* cw2 = d_in[8];
    const void* cb2 = d_in[9];
    const void* sw1 = d_in[10];
    const void* sb1 = d_in[11];
    const void* sw2 = d_in[12];
    const void* sb2 = d_in[13];
    const void* sw3 = d_in[14];
    const void* sb3 = d_in[15];
    // d_in[16..19] = wq,bq,wk,bk: unused (kv len-1 softmax == 1)
    const void* wv_ = d_in[20];
    const void* bv_ = d_in[21];
    const void* wo_ = d_in[22];
    const void* bo_ = d_in[23];
    const void* lng = d_in[24];
    const void* lnb = d_in[25];
    const void* fw  = d_in[26];
    const void* fb  = d_in[27];
    const void* fg  = d_in[28];
    const void* fbb = d_in[29];

    char* wsb = (char*)d_ws;
    size_t off = 0;
    auto take = [&](size_t n) { void* p = wsb + off; off += (n + 511) & ~(size_t)511; return p; };
    unsigned int* mb = (unsigned int*)take(4);
    float* w_sat = (float*)take((size_t)NB * NS * 8 * 4);
    float* w_uav = (float*)take((size_t)NB * NS * 8 * 4);
    float* den_s = (float*)take(256 * 4);
    float* den_u = (float*)take(256 * 4);
    float* satr  = (float*)take((size_t)NB * 8 * ND * 4);
    float* uavr  = (float*)take((size_t)NB * 8 * ND * 4);
    float* sa    = (float*)take((size_t)256 * ND * 4);
    float* ub    = (float*)take((size_t)256 * ND * 4);
    float* h1    = (float*)take((size_t)2048 * ND * 4);
    float* h2    = (float*)take((size_t)2048 * 384 * 4);
    float* sig   = (float*)take(2048 * 4);
    float* simac = (float*)take(64 * 4);
    int*   perm  = (int*)take(64);
    float* tb    = (float*)take((size_t)256 * ND * 4);
    float* vb    = (float*)take((size_t)256 * ND * 4);
    float* pb    = (float*)take((size_t)256 * ND * 4);
    float* pool  = (float*)take((size_t)256 * ND * 4);
    float* yb    = (float*)take((size_t)NB * ND * 4);
    // aliases inside h1 (first written much later by k_h1): split weights
    unsigned short* wsp = (unsigned short*)h1;
    unsigned short* iw1hi = wsp;
    unsigned short* iw1lo = wsp + (size_t)294912;
    unsigned short* cw1hi = wsp + (size_t)589824;
    unsigned short* cw1lo = wsp + (size_t)1179648;
    // alias inside h2 (first written by gemm later): num partials (3.1MB)
    float* nump4 = h2;
    // total ws ≈ 17.5 MB

    hipMemsetAsync(mb, 0, 4, stream);
    hipMemsetAsync(yb, 0, (size_t)NB * ND * 4, stream);

    k_probe<<<64, 256, 0, stream>>>((const unsigned short*)sat, mb);

    k_wsplit<<<512, 256, 0, stream>>>(iw1, 294912, mb, iw1hi, iw1lo);
    k_wsplit<<<512, 256, 0, stream>>>(cw1, 589824, mb, cw1hi, cw1lo);

    // region head (validated math; (256,3) occupancy setting) -> w directly
    k_regiong32<<<1024, 256, 0, stream>>>(sat, uav, iw1hi, iw1lo, ib1, iw2, ib2,
                                          cw1hi, cw1lo, cb1, cw2, cb2, mb, w_sat, w_uav);

    // downstream (validated)
    k_den<<<32, 256, 0, stream>>>(w_sat, den_s);
    k_den<<<32, 256, 0, stream>>>(w_uav, den_u);
    k_num4<<<dim3(4, 32), 192, 0, stream>>>(sat, w_sat, mb, nump4);
    k_regfin4<<<768, 256, 0, stream>>>(nump4, den_s, satr);
    k_num4<<<dim3(4, 32), 192, 0, stream>>>(uav, w_uav, mb, nump4);
    k_regfin4<<<768, 256, 0, stream>>>(nump4, den_u, uavr);

    k_gemm<<<dim3(12, 8, 1), 256, 0, stream>>>(satr, sw1, nullptr, 0.f, sa, 256, 768, 768, 1536, 0,   768, 0, 0, mb);
    k_gemm<<<dim3(12, 8, 1), 256, 0, stream>>>(uavr, sw1, nullptr, 0.f, ub, 256, 768, 768, 1536, 768, 768, 0, 0, mb);
    k_h1<<<2048, 256, 0, stream>>>(sa, ub, sb1, mb, h1);
    k_gemm<<<dim3(6, 64, 1), 256, 0, stream>>>(h1, sw2, sb2, 1.f, h2, 2048, 384, 768, 768, 0, 768, 1, 0, mb);
    k_simscore<<<2048, 64, 0, stream>>>(h2, sw3, sb3, mb, sig);
    k_simred<<<1, 64, 0, stream>>>(sig, simac);
    k_match<<<1, 64, 0, stream>>>(simac, perm);

    k_tbuild<<<256, 256, 0, stream>>>(satr, uavr, perm, tb);
    k_gemm<<<dim3(12, 8, 1), 256, 0, stream>>>(tb, wv_, bv_, 2.f, vb, 256, 768, 768, 768, 0, 768, 0, 0, mb);
    k_gemm<<<dim3(12, 8, 1), 256, 0, stream>>>(vb, wo_, bo_, 2.f, pb, 256, 768, 768, 768, 0, 768, 0, 0, mb);
    k_ln<<<256, 256, 0, stream>>>(pb, lng, lnb, mb, pool);

    k_gemm<<<dim3(12, 1, 8), 256, 0, stream>>>(pool, fw, nullptr, 0.f, yb, 32, 768, 6144, 6144, 0, 768, 0, 1, mb);
    k_fusln<<<32, 256, 0, stream>>>(yb, fb, fg, fbb, mb, d_out);
}

// Round 20
// 1122.769 us; speedup vs baseline: 1.4570x; 1.4341x over previous
//
#include <hip/hip_runtime.h>
#include <hip/hip_bf16.h>
#include <math.h>

// Problem: B=32, S=1024, D=768, R=8.
// CONFIRMED: inputs f32 (probe bf=false). Validated: k_regiong (r11/r17,
// BK=64 + __launch_bounds__(256,2): 610us, no spill — BEST), k_num4 (r10),
// downstream (r2). r18/r19: (256,4)/(256,3) both spill -> rejected.
// r20: revert region to r17 config; merge dual-view tail dispatches
// (k_num4v/k_regfin4v/k_den2/k_gemmsim) to fill the GPU (identical math).
// HARD RULE: ws <= ~18.6MB.
#define NB 32
#define NS 1024
#define ND 768
#define NR 8

#define BF_THRESH_BITS 0x461C4000u   // bits of 1e4f

typedef __bf16 v8bf __attribute__((ext_vector_type(8)));
typedef float  f32x4 __attribute__((ext_vector_type(4)));

__device__ __forceinline__ float us2f(unsigned short u) {
    return __uint_as_float(((unsigned int)u) << 16);
}
__device__ __forceinline__ float ldf(const void* p, size_t i, bool bf) {
    return bf ? us2f(((const unsigned short*)p)[i]) : ((const float*)p)[i];
}
__device__ __forceinline__ unsigned short f2b_rne(float x) {
    unsigned int u = __float_as_uint(x);
    return (unsigned short)((u + 0x7fffu + ((u >> 16) & 1u)) >> 16);
}

// ---------------------------------------------------------------------------
__global__ void k_probe(const unsigned short* __restrict__ s, unsigned int* __restrict__ mb) {
    int i = blockIdx.x * 256 + threadIdx.x;
    unsigned int v = 0;
    for (int k = i; k < (1 << 22); k += 16384) {
        unsigned int b = (((unsigned int)s[k]) << 16) & 0x7fffffffu;
        v = v > b ? v : b;
    }
#pragma unroll
    for (int m = 1; m < 64; m <<= 1) {
        unsigned int o = (unsigned int)__shfl_xor((int)v, m);
        v = v > o ? v : o;
    }
    if ((threadIdx.x & 63) == 0) atomicMax(mb, v);
}

__global__ void k_wsplit(const void* __restrict__ src, int n,
                         const unsigned int* __restrict__ mb,
                         unsigned short* __restrict__ hi, unsigned short* __restrict__ lo) {
    const bool bf = (*mb < BF_THRESH_BITS);
    for (int i = blockIdx.x * 256 + threadIdx.x; i < n; i += gridDim.x * 256) {
        float x = ldf(src, i, bf);
        unsigned short h = f2b_rne(x);
        hi[i] = h;
        lo[i] = f2b_rne(x - us2f(h));
    }
}

// ---------------------------------------------------------------------------
// k_regiong [r11-validated math, r17 occupancy config — BEST: 610us]
// ---------------------------------------------------------------------------
__global__ __launch_bounds__(256, 2) void k_regiong(
    const void* __restrict__ fs, const void* __restrict__ fu,
    const unsigned short* __restrict__ iw1hi, const unsigned short* __restrict__ iw1lo,
    const void* __restrict__ ib1, const void* __restrict__ iw2, const void* __restrict__ ib2,
    const unsigned short* __restrict__ cw1hi, const unsigned short* __restrict__ cw1lo,
    const void* __restrict__ cb1, const void* __restrict__ cw2, const void* __restrict__ cb2,
    const unsigned int* __restrict__ mb,
    float* __restrict__ ws, float* __restrict__ wu)
{
    __shared__ uint4 Ah[64 * 9], Al[64 * 9];
    __shared__ uint4 Bh[128 * 9], Bl[128 * 9];
    __shared__ float iw2s[384];
    __shared__ float part[64][9];

    const bool bf = (*mb < BF_THRESH_BITS);
    const int t = threadIdx.x;
    const bool isu = (blockIdx.x >= 512);
    const void* f = isu ? fu : fs;
    float* wout = isu ? wu : ws;
    const int row0 = (isu ? blockIdx.x - 512 : blockIdx.x) * 64;

    for (int i = t; i < 384; i += 256) iw2s[i] = ldf(iw2, i, bf);

    const int lane = t & 63;
    const int wv = t >> 6;
    const int l15 = lane & 15;
    const int g = lane >> 4;

    float impacc[4] = {0.f, 0.f, 0.f, 0.f};
    float lacc[8][4];
#pragma unroll
    for (int r = 0; r < 8; r++)
#pragma unroll
        for (int x = 0; x < 4; x++) lacc[r][x] = 0.f;

    for (int nt = 0; nt < 9; nt++) {
        const bool isimp = (nt < 3);
        const int colbase = isimp ? nt * 128 : nt * 128 - 384;
        const uint4* bsh = reinterpret_cast<const uint4*>(isimp ? iw1hi : cw1hi);
        const uint4* bsl = reinterpret_cast<const uint4*>(isimp ? iw1lo : cw1lo);

        f32x4 acc[8];
        int nn[8];
#pragma unroll
        for (int cf = 0; cf < 8; cf++) {
            int n = nt * 128 + cf * 16 + l15;
            nn[cf] = n;
            float bini = isimp ? ldf(ib1, n, bf) : ldf(cb1, n - 384, bf);
            f32x4 ini = {bini, bini, bini, bini};
            acc[cf] = ini;
        }

        for (int kc = 0; kc < 12; kc++) {
            __syncthreads();
#pragma unroll
            for (int p = 0; p < 4; p++) {
                int u = t + p * 256;
                int cc = u >> 3, j = u & 7;
                size_t src = (size_t)(colbase + cc) * 96 + kc * 8 + j;
                Bh[cc * 9 + j] = bsh[src];
                Bl[cc * 9 + j] = bsl[src];
            }
            if (bf) {
#pragma unroll
                for (int p = 0; p < 2; p++) {
                    int u = t + p * 256;
                    int rr = u >> 3, j = u & 7;
                    const uint4* asrc = reinterpret_cast<const uint4*>(
                        (const unsigned short*)f + (size_t)(row0 + rr) * ND);
                    Ah[rr * 9 + j] = asrc[kc * 8 + j];
                    uint4 z = {0, 0, 0, 0};
                    Al[rr * 9 + j] = z;
                }
            } else {
#pragma unroll
                for (int p = 0; p < 2; p++) {
                    int u = t + p * 256;
                    int rr = u >> 3, j = u & 7;
                    const float* fp = (const float*)f + (size_t)(row0 + rr) * ND + kc * 64 + j * 8;
                    float4 a = *reinterpret_cast<const float4*>(fp);
                    float4 b = *reinterpret_cast<const float4*>(fp + 4);
                    float v[8] = {a.x, a.y, a.z, a.w, b.x, b.y, b.z, b.w};
                    union { unsigned short us[8]; uint4 u4; } H, L;
#pragma unroll
                    for (int e = 0; e < 8; e++) {
                        unsigned short h = f2b_rne(v[e]);
                        H.us[e] = h;
                        L.us[e] = f2b_rne(v[e] - us2f(h));
                    }
                    Ah[rr * 9 + j] = H.u4;
                    Al[rr * 9 + j] = L.u4;
                }
            }
            __syncthreads();
#pragma unroll
            for (int kk = 0; kk < 2; kk++) {
                const int jj = kk * 4 + g;
                v8bf ah = __builtin_bit_cast(v8bf, Ah[(wv * 16 + l15) * 9 + jj]);
                v8bf al = __builtin_bit_cast(v8bf, Al[(wv * 16 + l15) * 9 + jj]);
#pragma unroll
                for (int cf = 0; cf < 8; cf++) {
                    v8bf bhv = __builtin_bit_cast(v8bf, Bh[(cf * 16 + l15) * 9 + jj]);
                    v8bf blv = __builtin_bit_cast(v8bf, Bl[(cf * 16 + l15) * 9 + jj]);
                    acc[cf] = __builtin_amdgcn_mfma_f32_16x16x32_bf16(ah, bhv, acc[cf], 0, 0, 0);
                    acc[cf] = __builtin_amdgcn_mfma_f32_16x16x32_bf16(al, bhv, acc[cf], 0, 0, 0);
                    acc[cf] = __builtin_amdgcn_mfma_f32_16x16x32_bf16(ah, blv, acc[cf], 0, 0, 0);
                }
            }
        }

        if (isimp) {
#pragma unroll
            for (int cf = 0; cf < 8; cf++) {
                float c = iw2s[nn[cf]];
#pragma unroll
                for (int x = 0; x < 4; x++)
                    impacc[x] = fmaf(fmaxf(acc[cf][x], 0.f), c, impacc[x]);
            }
        } else {
#pragma unroll
            for (int cf = 0; cf < 8; cf++) {
                const int nc = nn[cf] - 384;
                float h[4];
#pragma unroll
                for (int x = 0; x < 4; x++) h[x] = fmaxf(acc[cf][x], 0.f);
#pragma unroll
                for (int r = 0; r < 8; r++) {
                    float c = ldf(cw2, (size_t)r * ND + nc, bf);
#pragma unroll
                    for (int x = 0; x < 4; x++)
                        lacc[r][x] = fmaf(h[x], c, lacc[r][x]);
                }
            }
        }
    }

#pragma unroll
    for (int x = 0; x < 4; x++) {
        const int row = wv * 16 + g * 4 + x;
        float v = impacc[x];
        v += __shfl_xor(v, 1); v += __shfl_xor(v, 2);
        v += __shfl_xor(v, 4); v += __shfl_xor(v, 8);
        if (l15 == 0) part[row][0] = v;
#pragma unroll
        for (int r = 0; r < 8; r++) {
            float u = lacc[r][x];
            u += __shfl_xor(u, 1); u += __shfl_xor(u, 2);
            u += __shfl_xor(u, 4); u += __shfl_xor(u, 8);
            if (l15 == 0) part[row][1 + r] = u;
        }
    }
    __syncthreads();

    if (t < 64) {
        const int grow = row0 + t;
        float imp = part[t][0] + ldf(ib2, 0, bf);
        float lg[8], mx = -1e30f;
#pragma unroll
        for (int r = 0; r < 8; r++) { lg[r] = part[t][1 + r] + ldf(cb2, r, bf); mx = fmaxf(mx, lg[r]); }
        float ssum = 0.f;
#pragma unroll
        for (int r = 0; r < 8; r++) { lg[r] = expf(lg[r] - mx); ssum += lg[r]; }
        float inv = 1.f / ssum;
#pragma unroll
        for (int r = 0; r < 8; r++) wout[(size_t)grow * 8 + r] = imp * lg[r] * inv;
    }
}

// ---------------------------------------------------------------------------
// dual-view merged tail kernels (bodies identical to r2/r10-validated ones)
// ---------------------------------------------------------------------------
// k_den2: grid 64 (view = bx>>5, b = bx&31)
__global__ __launch_bounds__(256) void k_den2(
    const float* __restrict__ ws_, const float* __restrict__ wu_,
    float* __restrict__ den_s, float* __restrict__ den_u)
{
    __shared__ float red[256][8];
    const int view = blockIdx.x >> 5;
    const int b = blockIdx.x & 31;
    const float* w = view ? wu_ : ws_;
    float* den = view ? den_u : den_s;
    const int t = threadIdx.x;
    float acc[8];
#pragma unroll
    for (int r = 0; r < 8; r++) acc[r] = 0.f;
    for (int s = t; s < NS; s += 256)
#pragma unroll
        for (int r = 0; r < 8; r++) acc[r] += w[((size_t)b * NS + s) * 8 + r];
#pragma unroll
    for (int r = 0; r < 8; r++) red[t][r] = acc[r];
    __syncthreads();
    for (int off = 128; off > 0; off >>= 1) {
        if (t < off)
#pragma unroll
            for (int r = 0; r < 8; r++) red[t][r] += red[t + off][r];
        __syncthreads();
    }
    if (t < 8) den[b * 8 + t] = red[0][t];
}

// k_num4v: grid (4,32,2); nump layout (view, sc, b, r, d)
__global__ __launch_bounds__(192) void k_num4v(
    const void* __restrict__ fs, const void* __restrict__ fu,
    const float* __restrict__ ws_, const float* __restrict__ wu_,
    const unsigned int* __restrict__ mb, float* __restrict__ nump)
{
    __shared__ float wsh[256][8];
    const bool bf = (*mb < BF_THRESH_BITS);
    const int view = blockIdx.z;
    const void* f = view ? fu : fs;
    const float* w = view ? wu_ : ws_;
    float* np = nump + (size_t)view * 786432;
    const int sc = blockIdx.x, b = blockIdx.y, t = threadIdx.x;
    const int s0 = sc * 256;
    const float* wp = w + ((size_t)b * NS + s0) * 8;
    for (int i = t; i < 256 * 8; i += 192) ((float*)wsh)[i] = wp[i];
    __syncthreads();
    const int d0 = t * 4;
    float acc[8][4];
#pragma unroll
    for (int r = 0; r < 8; r++)
#pragma unroll
        for (int q = 0; q < 4; q++) acc[r][q] = 0.f;
    if (bf) {
        const unsigned short* fp = (const unsigned short*)f + ((size_t)b * NS + s0) * ND + d0;
        for (int s = 0; s < 256; s++) {
            ushort4 u = *reinterpret_cast<const ushort4*>(fp + (size_t)s * ND);
            float fv[4] = {us2f(u.x), us2f(u.y), us2f(u.z), us2f(u.w)};
#pragma unroll
            for (int r = 0; r < 8; r++) {
                float wr = wsh[s][r];
#pragma unroll
                for (int q = 0; q < 4; q++) acc[r][q] = fmaf(wr, fv[q], acc[r][q]);
            }
        }
    } else {
        const float* fp = (const float*)f + ((size_t)b * NS + s0) * ND + d0;
        for (int s = 0; s < 256; s++) {
            float4 v4 = *reinterpret_cast<const float4*>(fp + (size_t)s * ND);
            float fv[4] = {v4.x, v4.y, v4.z, v4.w};
#pragma unroll
            for (int r = 0; r < 8; r++) {
                float wr = wsh[s][r];
#pragma unroll
                for (int q = 0; q < 4; q++) acc[r][q] = fmaf(wr, fv[q], acc[r][q]);
            }
        }
    }
    float* op = np + ((size_t)sc * NB * 8 + (size_t)b * 8) * ND;
#pragma unroll
    for (int r = 0; r < 8; r++)
#pragma unroll
        for (int q = 0; q < 4; q++) op[r * ND + d0 + q] = acc[r][q];
}

// k_regfin4v: grid (768,2)
__global__ void k_regfin4v(const float* __restrict__ nump,
                           const float* __restrict__ den_s, const float* __restrict__ den_u,
                           float* __restrict__ satr, float* __restrict__ uavr)
{
    const int view = blockIdx.y;
    const float* np = nump + (size_t)view * 786432;
    const float* den = view ? den_u : den_s;
    float* reg = view ? uavr : satr;
    int i = blockIdx.x * 256 + threadIdx.x;   // 196608
    int br = i / ND;
    float s = np[i] + np[196608 + i] + np[2 * 196608 + i] + np[3 * 196608 + i];
    reg[i] = s / (den[br] + 1e-8f);
}

// k_gemmsim: sa/ub pair merged; grid (12,8,2). M=256,N=768,K=768,ldw=1536.
__global__ __launch_bounds__(256) void k_gemmsim(
    const float* __restrict__ satr, const float* __restrict__ uavr,
    const void* __restrict__ sw1, const unsigned int* __restrict__ mb,
    float* __restrict__ sa, float* __restrict__ ub)
{
    __shared__ float As[32][17];
    __shared__ float Ws[64][17];
    const bool bf = (*mb < BF_THRESH_BITS);
    const int view = blockIdx.z;
    const float* A = view ? uavr : satr;
    float* C = view ? ub : sa;
    const int col_off = view ? 768 : 0;
    const int t = threadIdx.x;
    const int n0 = blockIdx.x * 64, m0 = blockIdx.y * 32;
    const int tc = t & 15, tr = t >> 4;
    float acc[2][4] = {{0, 0, 0, 0}, {0, 0, 0, 0}};
    for (int k0 = 0; k0 < 768; k0 += 16) {
        __syncthreads();
        for (int i = t; i < 512; i += 256) {
            int r = i >> 4, k = i & 15;
            As[r][k] = A[(size_t)(m0 + r) * 768 + k0 + k];
        }
        for (int i = t; i < 1024; i += 256) {
            int r = i >> 4, k = i & 15;
            Ws[r][k] = ldf(sw1, (size_t)(n0 + r) * 1536 + col_off + k0 + k, bf);
        }
        __syncthreads();
#pragma unroll
        for (int kk = 0; kk < 16; kk++) {
            float a0 = As[tr * 2 + 0][kk], a1 = As[tr * 2 + 1][kk];
#pragma unroll
            for (int c = 0; c < 4; c++) {
                float wv = Ws[tc * 4 + c][kk];
                acc[0][c] = fmaf(a0, wv, acc[0][c]);
                acc[1][c] = fmaf(a1, wv, acc[1][c]);
            }
        }
    }
#pragma unroll
    for (int rr = 0; rr < 2; rr++) {
        int row = m0 + tr * 2 + rr;
#pragma unroll
        for (int c = 0; c < 4; c++) {
            int col = n0 + tc * 4 + c;
            C[(size_t)row * 768 + col] = acc[rr][c];
        }
    }
}

// ---------------------------------------------------------------------------
// remaining validated pipeline [r2]
// ---------------------------------------------------------------------------
__global__ __launch_bounds__(256) void k_gemm(
    const float* __restrict__ A, const void* __restrict__ W,
    const void* __restrict__ bias, float bscale,
    float* __restrict__ C, int M, int N, int K, int ldw, int col_off,
    int kchunk, int relu_fl, int atomic_fl, const unsigned int* __restrict__ mb)
{
    __shared__ float As[32][17];
    __shared__ float Ws[64][17];
    const bool bf = (*mb < BF_THRESH_BITS);
    const int t = threadIdx.x;
    const int n0 = blockIdx.x * 64, m0 = blockIdx.y * 32;
    const int kbase = blockIdx.z * kchunk;
    const int tc = t & 15, tr = t >> 4;
    float acc[2][4] = {{0, 0, 0, 0}, {0, 0, 0, 0}};
    for (int k0 = kbase; k0 < kbase + kchunk; k0 += 16) {
        __syncthreads();
        for (int i = t; i < 512; i += 256) {
            int r = i >> 4, k = i & 15;
            As[r][k] = A[(size_t)(m0 + r) * K + k0 + k];
        }
        for (int i = t; i < 1024; i += 256) {
            int r = i >> 4, k = i & 15;
            Ws[r][k] = ldf(W, (size_t)(n0 + r) * ldw + col_off + k0 + k, bf);
        }
        __syncthreads();
#pragma unroll
        for (int kk = 0; kk < 16; kk++) {
            float a0 = As[tr * 2 + 0][kk], a1 = As[tr * 2 + 1][kk];
#pragma unroll
            for (int c = 0; c < 4; c++) {
                float wv = Ws[tc * 4 + c][kk];
                acc[0][c] = fmaf(a0, wv, acc[0][c]);
                acc[1][c] = fmaf(a1, wv, acc[1][c]);
            }
        }
    }
#pragma unroll
    for (int rr = 0; rr < 2; rr++) {
        int row = m0 + tr * 2 + rr;
#pragma unroll
        for (int c = 0; c < 4; c++) {
            int col = n0 + tc * 4 + c;
            float v = acc[rr][c];
            if (atomic_fl) {
                atomicAdd(&C[(size_t)row * N + col], v);
            } else {
                if (bias) v += ldf(bias, col, bf) * bscale;
                if (relu_fl) v = fmaxf(v, 0.f);
                C[(size_t)row * N + col] = v;
            }
        }
    }
}

__global__ void k_h1(const float* __restrict__ sa, const float* __restrict__ ub,
                     const void* __restrict__ b1, const unsigned int* __restrict__ mb,
                     float* __restrict__ h1) {
    const bool bf = (*mb < BF_THRESH_BITS);
    const int p = blockIdx.x;
    const int b = p >> 6, i = (p >> 3) & 7, j = p & 7;
    const float* sap = sa + (size_t)(b * 8 + i) * ND;
    const float* ubp = ub + (size_t)(b * 8 + j) * ND;
    float* o = h1 + (size_t)p * ND;
    for (int k = threadIdx.x; k < ND; k += 256)
        o[k] = fmaxf(sap[k] + ubp[k] + ldf(b1, k, bf), 0.f);
}

__global__ void k_simscore(const float* __restrict__ h2, const void* __restrict__ w3,
                           const void* __restrict__ b3, const unsigned int* __restrict__ mb,
                           float* __restrict__ sig) {
    const bool bf = (*mb < BF_THRESH_BITS);
    const int p = blockIdx.x;
    const int lane = threadIdx.x;
    const float* hp = h2 + (size_t)p * 384;
    float v = 0.f;
    for (int k = lane; k < 384; k += 64) v = fmaf(hp[k], ldf(w3, k, bf), v);
#pragma unroll
    for (int m = 1; m < 64; m <<= 1) v += __shfl_xor(v, m);
    if (lane == 0) sig[p] = 1.f / (1.f + expf(-(v + ldf(b3, 0, bf))));
}

__global__ void k_simred(const float* __restrict__ sig, float* __restrict__ simacc) {
    const int q = threadIdx.x;
    float s = 0.f;
    for (int b = 0; b < 32; b++) s += sig[b * 64 + q];
    simacc[q] = s * (1.f / 32.f);
}

__global__ void k_match(const float* __restrict__ simacc, int* __restrict__ perm) {
    if (threadIdx.x == 0) {
        float sim[64];
        bool used[8] = {false, false, false, false, false, false, false, false};
        for (int i = 0; i < 64; i++) sim[i] = simacc[i];
        for (int i = 0; i < 8; i++) {
            int bj = 0; float bvv = -2.f;
            for (int j = 0; j < 8; j++) {
                float v = used[j] ? -1.f : sim[i * 8 + j];
                if (v > bvv) { bvv = v; bj = j; }
            }
            used[bj] = true;
            perm[i] = bj;
        }
    }
}

__global__ void k_tbuild(const float* __restrict__ satr, const float* __restrict__ uavr,
                         const int* __restrict__ perm, float* __restrict__ tb) {
    const int row = blockIdx.x;
    const int b = row >> 3, i = row & 7;
    const float* sp = satr + (size_t)row * ND;
    const float* up = uavr + (size_t)(b * 8 + perm[i]) * ND;
    float* o = tb + (size_t)row * ND;
    for (int k = threadIdx.x; k < ND; k += 256) o[k] = sp[k] + up[k];
}

__global__ __launch_bounds__(256) void k_ln(const float* __restrict__ x,
                                            const void* __restrict__ g,
                                            const void* __restrict__ b,
                                            const unsigned int* __restrict__ mb,
                                            float* __restrict__ o) {
    __shared__ float t0[4], t1[4];
    const bool bf = (*mb < BF_THRESH_BITS);
    const int row = blockIdx.x, tid = threadIdx.x;
    const float* xp = x + (size_t)row * ND;
    float v0 = xp[tid], v1 = xp[tid + 256], v2 = xp[tid + 512];
    float s = v0 + v1 + v2;
#pragma unroll
    for (int m = 1; m < 64; m <<= 1) s += __shfl_xor(s, m);
    if ((tid & 63) == 0) t0[tid >> 6] = s;
    __syncthreads();
    float mean = (t0[0] + t0[1] + t0[2] + t0[3]) * (1.f / 768.f);
    float d0 = v0 - mean, d1 = v1 - mean, d2 = v2 - mean;
    float q = d0 * d0 + d1 * d1 + d2 * d2;
#pragma unroll
    for (int m = 1; m < 64; m <<= 1) q += __shfl_xor(q, m);
    if ((tid & 63) == 0) t1[tid >> 6] = q;
    __syncthreads();
    float var = (t1[0] + t1[1] + t1[2] + t1[3]) * (1.f / 768.f);
    float inv = 1.f / sqrtf(var + 1e-5f);
    float* op = o + (size_t)row * ND;
    op[tid]       = d0 * inv * ldf(g, tid, bf)       + ldf(b, tid, bf);
    op[tid + 256] = d1 * inv * ldf(g, tid + 256, bf) + ldf(b, tid + 256, bf);
    op[tid + 512] = d2 * inv * ldf(g, tid + 512, bf) + ldf(b, tid + 512, bf);
}

__global__ __launch_bounds__(256) void k_fusln(const float* __restrict__ y,
                                               const void* __restrict__ fb,
                                               const void* __restrict__ g,
                                               const void* __restrict__ bb,
                                               const unsigned int* __restrict__ mb,
                                               void* __restrict__ out) {
    __shared__ float t0[4], t1[4];
    const bool bf = (*mb < BF_THRESH_BITS);
    const int row = blockIdx.x, tid = threadIdx.x;
    const float* yp = y + (size_t)row * ND;
    float v0 = yp[tid] + ldf(fb, tid, bf);
    float v1 = yp[tid + 256] + ldf(fb, tid + 256, bf);
    float v2 = yp[tid + 512] + ldf(fb, tid + 512, bf);
    float s = v0 + v1 + v2;
#pragma unroll
    for (int m = 1; m < 64; m <<= 1) s += __shfl_xor(s, m);
    if ((tid & 63) == 0) t0[tid >> 6] = s;
    __syncthreads();
    float mean = (t0[0] + t0[1] + t0[2] + t0[3]) * (1.f / 768.f);
    float d0 = v0 - mean, d1 = v1 - mean, d2 = v2 - mean;
    float q = d0 * d0 + d1 * d1 + d2 * d2;
#pragma unroll
    for (int m = 1; m < 64; m <<= 1) q += __shfl_xor(q, m);
    if ((tid & 63) == 0) t1[tid >> 6] = q;
    __syncthreads();
    float var = (t1[0] + t1[1] + t1[2] + t1[3]) * (1.f / 768.f);
    float inv = 1.f / sqrtf(var + 1e-5f);
    float r0 = fmaxf(d0 * inv * ldf(g, tid, bf)       + ldf(bb, tid, bf), 0.f);
    float r1 = fmaxf(d1 * inv * ldf(g, tid + 256, bf) + ldf(bb, tid + 256, bf), 0.f);
    float r2 = fmaxf(d2 * inv * ldf(g, tid + 512, bf) + ldf(bb, tid + 512, bf), 0.f);
    if (bf) {
        __hip_bfloat16* op = (__hip_bfloat16*)out + (size_t)row * ND;
        op[tid]       = __float2bfloat16(r0);
        op[tid + 256] = __float2bfloat16(r1);
        op[tid + 512] = __float2bfloat16(r2);
    } else {
        float* op = (float*)out + (size_t)row * ND;
        op[tid]       = r0;
        op[tid + 256] = r1;
        op[tid + 512] = r2;
    }
}

// ---------------------------------------------------------------------------
extern "C" void kernel_launch(void* const* d_in, const int* in_sizes, int n_in,
                              void* d_out, int out_size, void* d_ws, size_t ws_size,
                              hipStream_t stream)
{
    (void)in_sizes; (void)n_in; (void)out_size; (void)ws_size;
    const void* sat = d_in[0];
    const void* uav = d_in[1];
    const void* iw1 = d_in[2];
    const void* ib1 = d_in[3];
    const void* iw2 = d_in[4];
    const void* ib2 = d_in[5];
    const void* cw1 = d_in[6];
    const void* cb1 = d_in[7];
    const void* cw2 = d_in[8];
    const void* cb2 = d_in[9];
    const void* sw1 = d_in[10];
    const void* sb1 = d_in[11];
    const void* sw2 = d_in[12];
    const void* sb2 = d_in[13];
    const void* sw3 = d_in[14];
    const void* sb3 = d_in[15];
    // d_in[16..19] = wq,bq,wk,bk: unused (kv len-1 softmax == 1)
    const void* wv_ = d_in[20];
    const void* bv_ = d_in[21];
    const void* wo_ = d_in[22];
    const void* bo_ = d_in[23];
    const void* lng = d_in[24];
    const void* lnb = d_in[25];
    const void* fw  = d_in[26];
    const void* fb  = d_in[27];
    const void* fg  = d_in[28];
    const void* fbb = d_in[29];

    char* wsb = (char*)d_ws;
    size_t off = 0;
    auto take = [&](size_t n) { void* p = wsb + off; off += (n + 511) & ~(size_t)511; return p; };
    unsigned int* mb = (unsigned int*)take(4);
    float* w_sat = (float*)take((size_t)NB * NS * 8 * 4);
    float* w_uav = (float*)take((size_t)NB * NS * 8 * 4);
    float* den_s = (float*)take(256 * 4);
    float* den_u = (float*)take(256 * 4);
    float* satr  = (float*)take((size_t)NB * 8 * ND * 4);
    float* uavr  = (float*)take((size_t)NB * 8 * ND * 4);
    float* sa    = (float*)take((size_t)256 * ND * 4);
    float* ub    = (float*)take((size_t)256 * ND * 4);
    float* h1    = (float*)take((size_t)2048 * ND * 4);
    float* h2    = (float*)take((size_t)2048 * 384 * 4);
    float* sig   = (float*)take(2048 * 4);
    float* simac = (float*)take(64 * 4);
    int*   perm  = (int*)take(64);
    float* tb    = (float*)take((size_t)256 * ND * 4);
    float* vb    = (float*)take((size_t)256 * ND * 4);
    float* pb    = (float*)take((size_t)256 * ND * 4);
    float* pool  = (float*)take((size_t)256 * ND * 4);
    float* yb    = (float*)take((size_t)NB * ND * 4);
    // aliases inside h1 (6.29MB):
    //  phase 1 (until region done): split weights, first 3.54MB
    //  phase 2 (num/regfin): nump 2 views x 3.146MB = 6.29MB (fills h1)
    //  phase 3: k_h1 output
    unsigned short* wsp = (unsigned short*)h1;
    unsigned short* iw1hi = wsp;
    unsigned short* iw1lo = wsp + (size_t)294912;
    unsigned short* cw1hi = wsp + (size_t)589824;
    unsigned short* cw1lo = wsp + (size_t)1179648;
    float* nump = h1;                       // (2,4,32,8,768) floats
    // total ws ≈ 14.4 MB

    hipMemsetAsync(mb, 0, 4, stream);
    hipMemsetAsync(yb, 0, (size_t)NB * ND * 4, stream);

    k_probe<<<64, 256, 0, stream>>>((const unsigned short*)sat, mb);

    k_wsplit<<<512, 256, 0, stream>>>(iw1, 294912, mb, iw1hi, iw1lo);
    k_wsplit<<<512, 256, 0, stream>>>(cw1, 589824, mb, cw1hi, cw1lo);

    // region head (r17 best config) -> w directly
    k_regiong<<<1024, 256, 0, stream>>>(sat, uav, iw1hi, iw1lo, ib1, iw2, ib2,
                                        cw1hi, cw1lo, cb1, cw2, cb2, mb, w_sat, w_uav);

    // merged dual-view tail
    k_den2<<<64, 256, 0, stream>>>(w_sat, w_uav, den_s, den_u);
    k_num4v<<<dim3(4, 32, 2), 192, 0, stream>>>(sat, uav, w_sat, w_uav, mb, nump);
    k_regfin4v<<<dim3(768, 2), 256, 0, stream>>>(nump, den_s, den_u, satr, uavr);

    k_gemmsim<<<dim3(12, 8, 2), 256, 0, stream>>>(satr, uavr, sw1, mb, sa, ub);
    k_h1<<<2048, 256, 0, stream>>>(sa, ub, sb1, mb, h1);
    k_gemm<<<dim3(6, 64, 1), 256, 0, stream>>>(h1, sw2, sb2, 1.f, h2, 2048, 384, 768, 768, 0, 768, 1, 0, mb);
    k_simscore<<<2048, 64, 0, stream>>>(h2, sw3, sb3, mb, sig);
    k_simred<<<1, 64, 0, stream>>>(sig, simac);
    k_match<<<1, 64, 0, stream>>>(simac, perm);

    k_tbuild<<<256, 256, 0, stream>>>(satr, uavr, perm, tb);
    k_gemm<<<dim3(12, 8, 1), 256, 0, stream>>>(tb, wv_, bv_, 2.f, vb, 256, 768, 768, 768, 0, 768, 0, 0, mb);
    k_gemm<<<dim3(12, 8, 1), 256, 0, stream>>>(vb, wo_, bo_, 2.f, pb, 256, 768, 768, 768, 0, 768, 0, 0, mb);
    k_ln<<<256, 256, 0, stream>>>(pb, lng, lnb, mb, pool);

    k_gemm<<<dim3(12, 1, 8), 256, 0, stream>>>(pool, fw, nullptr, 0.f, yb, 32, 768, 6144, 6144, 0, 768, 0, 1, mb);
    k_fusln<<<32, 256, 0, stream>>>(yb, fb, fg, fbb, mb, d_out);
}